// Round 1
// baseline (131557.495 us; speedup 1.0000x reference)
//
#include <hip/hip_runtime.h>
#include <hip/hip_cooperative_groups.h>

namespace cg = cooperative_groups;

typedef _Float16 half_t;
typedef _Float16 f16x8 __attribute__((ext_vector_type(8)));
typedef float f32x4 __attribute__((ext_vector_type(4)));

#define T_LEN 512
#define BATCH 128
#define INDIM 800
#define HID   400
#define NG    3200   // 2 dirs * 4H

// ---------------- cast fp32 -> fp16 ----------------
__global__ void cast_f32_f16(const float* __restrict__ src, half_t* __restrict__ dst, size_t n) {
    size_t i = (size_t)blockIdx.x * blockDim.x + threadIdx.x;
    size_t stride = (size_t)gridDim.x * blockDim.x;
    for (; i < n; i += stride) dst[i] = (half_t)src[i];
}

// ---------------- input GEMM: C[M,3200] = A[M,800] @ W[3200,800]^T (fp16 in, fp16 out, fp32 acc)
__global__ __launch_bounds__(256)
void gemm_f16(const half_t* __restrict__ A, const half_t* __restrict__ Bw,
              half_t* __restrict__ C) {
    __shared__ half_t As[128 * 32];
    __shared__ half_t Bs[128 * 32];
    const int tid  = threadIdx.x;
    const int m0   = blockIdx.x * 128;
    const int n0   = blockIdx.y * 128;
    const int w    = tid >> 6;
    const int lane = tid & 63;
    const int wm   = (w & 1) * 64;
    const int wn   = (w >> 1) * 64;
    const int lr   = lane & 15;
    const int kb   = (lane >> 4) * 8;

    f32x4 acc[4][4] = {};

    for (int k0 = 0; k0 < INDIM; k0 += 32) {
        __syncthreads();
        #pragma unroll
        for (int it = 0; it < 2; ++it) {
            int c   = tid + it * 256;      // 0..511 chunks of 8 halfs
            int row = c >> 2;
            int kp  = (c & 3) * 8;
            *(f16x8*)(As + row * 32 + kp) = *(const f16x8*)(A  + (size_t)(m0 + row) * INDIM + k0 + kp);
            *(f16x8*)(Bs + row * 32 + kp) = *(const f16x8*)(Bw + (size_t)(n0 + row) * INDIM + k0 + kp);
        }
        __syncthreads();
        f16x8 a[4], b[4];
        #pragma unroll
        for (int i = 0; i < 4; ++i) a[i] = *(const f16x8*)(As + (wm + i * 16 + lr) * 32 + kb);
        #pragma unroll
        for (int j = 0; j < 4; ++j) b[j] = *(const f16x8*)(Bs + (wn + j * 16 + lr) * 32 + kb);
        #pragma unroll
        for (int i = 0; i < 4; ++i)
            #pragma unroll
            for (int j = 0; j < 4; ++j)
                acc[i][j] = __builtin_amdgcn_mfma_f32_16x16x32_f16(a[i], b[j], acc[i][j], 0, 0, 0);
    }

    const int lq = lane >> 4;
    #pragma unroll
    for (int i = 0; i < 4; ++i)
        #pragma unroll
        for (int j = 0; j < 4; ++j)
            #pragma unroll
            for (int r = 0; r < 4; ++r) {
                int m = m0 + wm + i * 16 + lq * 4 + r;
                int n = n0 + wn + j * 16 + lr;
                C[(size_t)m * NG + n] = (half_t)acc[i][j][r];
            }
}

// ---------------- cooperative bidirectional scan for one layer ----------------
// grid = 200 blocks: blockIdx.x/100 = direction, (blockIdx.x%100)*4 = first hidden unit
__global__ __launch_bounds__(256)
void scan_kernel(const float* __restrict__ Whh_all, const float* __restrict__ bih,
                 const float* __restrict__ bhh, const half_t* __restrict__ gates,
                 const int* __restrict__ bs, float* __restrict__ h_pub,
                 half_t* __restrict__ out16, float* __restrict__ out32, int layer) {
    __shared__ float Wsh[16][404];   // padded: bank-spread for f32x4 reads
    __shared__ float Gsh[16][132];
    cg::grid_group gridg = cg::this_grid();

    const int tid = threadIdx.x;
    const int d   = blockIdx.x / 100;
    const int u0  = (blockIdx.x % 100) * 4;
    const float* Wbase = Whh_all + (size_t)(layer * 2 + d) * 1600 * HID;

    // load 16 Whh rows (i,f,g,o for 4 units) into LDS
    for (int idx = tid; idx < 16 * HID; idx += 256) {
        int gi = idx / HID, k = idx - gi * HID;
        int row = (gi >> 2) * HID + u0 + (gi & 3);
        Wsh[gi][k] = Wbase[(size_t)row * HID + k];
    }

    // cell-phase identity + persistent state
    const int b = tid & 127, s = tid >> 7;
    float bias[2][4];
    float c_reg[2] = {0.f, 0.f}, h_reg[2] = {0.f, 0.f};
    #pragma unroll
    for (int q = 0; q < 2; ++q) {
        int u = u0 + s + 2 * q;
        #pragma unroll
        for (int ty = 0; ty < 4; ++ty) {
            size_t bi = (size_t)(layer * 2 + d) * 1600 + ty * HID + u;
            bias[q][ty] = bih[bi] + bhh[bi];
        }
    }
    const int gi = tid & 15, bl = tid >> 4;
    int cur = 0;
    __syncthreads();

    for (int t = 0; t < T_LEN; ++t) {
        const int tp = d ? (T_LEN - 1 - t) : t;

        // phase 1: recurrent gates for 16 rows x 128 batch
        const f32x4* Wrow = (const f32x4*)(&Wsh[gi][0]);
        const f32x4* Hc   = (const f32x4*)(h_pub + (size_t)(cur * 2 + d) * BATCH * HID);
        float acc[8] = {0, 0, 0, 0, 0, 0, 0, 0};
        for (int k4 = 0; k4 < HID / 4; ++k4) {
            f32x4 wv = Wrow[k4];
            #pragma unroll
            for (int j = 0; j < 8; ++j) {
                f32x4 hv = Hc[(size_t)(bl + 16 * j) * (HID / 4) + k4];
                acc[j] += wv[0] * hv[0] + wv[1] * hv[1] + wv[2] * hv[2] + wv[3] * hv[3];
            }
        }
        #pragma unroll
        for (int j = 0; j < 8; ++j) Gsh[gi][bl + 16 * j] = acc[j];
        __syncthreads();

        // phase 2: LSTM cell for 2 units per thread
        const int bst = bs[tp];
        const bool active = b < bst;
        float* Hn = h_pub + (size_t)((cur ^ 1) * 2 + d) * BATCH * HID;
        #pragma unroll
        for (int q = 0; q < 2; ++q) {
            int uu = s + 2 * q, u = u0 + uu;
            size_t gbase = ((size_t)tp * BATCH + b) * NG + d * 1600 + u;
            float gI = Gsh[uu][b]      + (float)gates[gbase]         + bias[q][0];
            float gF = Gsh[4 + uu][b]  + (float)gates[gbase + 400]   + bias[q][1];
            float gG = Gsh[8 + uu][b]  + (float)gates[gbase + 800]   + bias[q][2];
            float gO = Gsh[12 + uu][b] + (float)gates[gbase + 1200]  + bias[q][3];
            float iv = 1.f / (1.f + __expf(-gI));
            float fv = 1.f / (1.f + __expf(-gF));
            float gv = 1.f - 2.f / (1.f + __expf(2.f * gG));
            float ov = 1.f / (1.f + __expf(-gO));
            float cn = fv * c_reg[q] + iv * gv;
            float hn = ov * (1.f - 2.f / (1.f + __expf(2.f * cn)));
            if (active) { c_reg[q] = cn; h_reg[q] = hn; }
            Hn[(size_t)b * HID + u] = h_reg[q];
            float outv = active ? h_reg[q] : 0.f;
            size_t oidx = ((size_t)tp * BATCH + b) * 800 + d * HID + u;
            if (out32) out32[oidx] = outv;
            else       out16[oidx] = (half_t)outv;
        }
        __threadfence();
        gridg.sync();
        cur ^= 1;
    }
}

// ---------------- host ----------------
extern "C" void kernel_launch(void* const* d_in, const int* in_sizes, int n_in,
                              void* d_out, int out_size, void* d_ws, size_t ws_size,
                              hipStream_t stream) {
    const float* x    = (const float*)d_in[0];
    const float* Wih  = (const float*)d_in[1];
    const float* Whh  = (const float*)d_in[2];
    const float* bih  = (const float*)d_in[3];
    const float* bhh  = (const float*)d_in[4];
    const int*   bs   = (const int*)d_in[5];
    float*       out  = (float*)d_out;

    char* ws = (char*)d_ws;
    const size_t XBUF_B  = (size_t)T_LEN * BATCH * INDIM * 2;      // 104,857,600
    const size_t WIH_B   = (size_t)3 * 2 * 1600 * INDIM * 2;       //  15,360,000
    const size_t GATES_B = (size_t)T_LEN * BATCH * NG * 2;         // 419,430,400
    const size_t HPUB_B  = (size_t)2 * 2 * BATCH * HID * 4;        //   1,638,400

    half_t* xbuf0 = (half_t*)(ws);
    half_t* xbuf1 = (half_t*)(ws + XBUF_B);
    half_t* Wih16 = (half_t*)(ws + 2 * XBUF_B);
    half_t* gates = (half_t*)(ws + 2 * XBUF_B + WIH_B);
    float*  h_pub = (float*) (ws + 2 * XBUF_B + WIH_B + GATES_B);
    (void)HPUB_B; (void)ws_size; (void)in_sizes; (void)n_in; (void)out_size;

    // casts
    cast_f32_f16<<<2048, 256, 0, stream>>>(x,   xbuf0, (size_t)T_LEN * BATCH * INDIM);
    cast_f32_f16<<<2048, 256, 0, stream>>>(Wih, Wih16, (size_t)3 * 2 * 1600 * INDIM);

    for (int l = 0; l < 3; ++l) {
        const half_t* xin    = (l == 0) ? xbuf0 : ((l == 1) ? xbuf1 : xbuf0);
        half_t*       xout16 = (l == 0) ? xbuf1 : ((l == 1) ? xbuf0 : (half_t*)nullptr);
        float*        out32  = (l == 2) ? out : (float*)nullptr;

        gemm_f16<<<dim3(512, 25), 256, 0, stream>>>(xin, Wih16 + (size_t)l * NG * INDIM, gates);

        hipMemsetAsync(h_pub, 0, HPUB_B, stream);

        const float* WhhA = Whh; const float* bihA = bih; const float* bhhA = bhh;
        const half_t* gatesA = gates; const int* bsA = bs; float* hpubA = h_pub;
        int layer = l;
        void* args[] = {(void*)&WhhA, (void*)&bihA, (void*)&bhhA, (void*)&gatesA,
                        (void*)&bsA, (void*)&hpubA, (void*)&xout16, (void*)&out32, (void*)&layer};
        hipLaunchCooperativeKernel((void*)scan_kernel, dim3(200), dim3(256), args, 0, stream);
    }
}

// Round 2
// 49572.220 us; speedup vs baseline: 2.6539x; 2.6539x over previous
//
#include <hip/hip_runtime.h>

typedef _Float16 half_t;
typedef _Float16 f16x8 __attribute__((ext_vector_type(8)));
typedef _Float16 f16x4 __attribute__((ext_vector_type(4)));
typedef float f32x4 __attribute__((ext_vector_type(4)));

#define T_LEN 512
#define BATCH 128
#define INDIM 800
#define HID   400
#define NG    3200   // 2 dirs * 4H
#define KP    416    // recurrent K padded to 13*32
#define BPD   50     // blocks per direction
#define UPB   8      // units per block (32 gate rows)

// ---------------- cast fp32 -> fp16 ----------------
__global__ void cast_f32_f16(const float* __restrict__ src, half_t* __restrict__ dst, size_t n) {
    size_t i = (size_t)blockIdx.x * blockDim.x + threadIdx.x;
    size_t stride = (size_t)gridDim.x * blockDim.x;
    for (; i < n; i += stride) dst[i] = (half_t)src[i];
}

// ---------------- input GEMM ----------------
// A[M=T*B, 800] @ W[3200, 800]^T, output TRANSPOSED per t-tile:
// gates_T[((t*3200)+n)*128 + b]   (fp16, fp32 accum)
__global__ __launch_bounds__(256)
void gemm_f16(const half_t* __restrict__ A, const half_t* __restrict__ Bw,
              half_t* __restrict__ C) {
    __shared__ half_t As[128 * 32];
    __shared__ half_t Bs[128 * 32];
    const int tid  = threadIdx.x;
    const int m0   = blockIdx.x * 128;     // m-tile == one t (128 batches)
    const int n0   = blockIdx.y * 128;
    const int w    = tid >> 6;
    const int lane = tid & 63;
    const int wm   = (w & 1) * 64;
    const int wn   = (w >> 1) * 64;
    const int lr   = lane & 15;
    const int kb   = (lane >> 4) * 8;

    f32x4 acc[4][4] = {};

    for (int k0 = 0; k0 < INDIM; k0 += 32) {
        __syncthreads();
        #pragma unroll
        for (int it = 0; it < 2; ++it) {
            int c   = tid + it * 256;      // 512 chunks of 8 halfs
            int row = c >> 2;
            int kp  = (c & 3) * 8;
            *(f16x8*)(As + row * 32 + kp) = *(const f16x8*)(A  + (size_t)(m0 + row) * INDIM + k0 + kp);
            *(f16x8*)(Bs + row * 32 + kp) = *(const f16x8*)(Bw + (size_t)(n0 + row) * INDIM + k0 + kp);
        }
        __syncthreads();
        f16x8 a[4], b[4];
        #pragma unroll
        for (int i = 0; i < 4; ++i) a[i] = *(const f16x8*)(As + (wm + i * 16 + lr) * 32 + kb);
        #pragma unroll
        for (int j = 0; j < 4; ++j) b[j] = *(const f16x8*)(Bs + (wn + j * 16 + lr) * 32 + kb);
        // swapped operands -> C row = n (gate row), col = m (batch)
        #pragma unroll
        for (int i = 0; i < 4; ++i)
            #pragma unroll
            for (int j = 0; j < 4; ++j)
                acc[i][j] = __builtin_amdgcn_mfma_f32_16x16x32_f16(b[j], a[i], acc[i][j], 0, 0, 0);
    }

    const int t  = blockIdx.x;
    const int lq = lane >> 4;
    #pragma unroll
    for (int i = 0; i < 4; ++i)
        #pragma unroll
        for (int j = 0; j < 4; ++j)
            #pragma unroll
            for (int r = 0; r < 4; ++r) {
                int n  = n0 + wn + j * 16 + lq * 4 + r;
                int bb = wm + i * 16 + lr;
                C[((size_t)t * NG + n) * BATCH + bb] = (half_t)acc[i][j][r];
            }
}

// ---------------- persistent bidirectional scan (one layer) ----------------
// grid = 100 blocks: [0,50) fwd, [50,100) bwd; each owns 8 units (32 gate rows).
// Per-direction barrier: monotonic counter in cnt[d].
__global__ __launch_bounds__(256)
void scan_kernel(const float* __restrict__ Whh_all, const float* __restrict__ bih,
                 const float* __restrict__ bhh, const half_t* __restrict__ gates,
                 const int* __restrict__ bs, half_t* __restrict__ h_pub,
                 int* __restrict__ cnt,
                 half_t* __restrict__ out16, float* __restrict__ out32, int layer) {
    __shared__ half_t Wsh[32][424];   // 424 stride: spreads rows across banks
    __shared__ float  Gsh[32][132];

    const int tid = threadIdx.x;
    const int d   = blockIdx.x / BPD;
    const int blk = blockIdx.x % BPD;
    const int u0  = blk * UPB;
    const float* Wbase = Whh_all + (size_t)(layer * 2 + d) * 1600 * HID;

    // stage 32 Whh rows (4 types x 8 units), fp32 -> fp16, zero-pad K to 416
    for (int idx = tid; idx < 32 * KP; idx += 256) {
        int g = idx / KP, k = idx - g * KP;
        int type = g >> 3, usub = g & 7;
        float v = (k < HID) ? Wbase[(size_t)(type * HID + u0 + usub) * HID + k] : 0.f;
        Wsh[g][k] = (half_t)v;
    }

    const int lane = tid & 63, w = tid >> 6;
    const int lr = lane & 15, kq = (lane >> 4) * 8;
    const int b = tid & 127, s = tid >> 7;

    float bias[4][4];
    float c_reg[4] = {0.f, 0.f, 0.f, 0.f}, h_reg[4] = {0.f, 0.f, 0.f, 0.f};
    #pragma unroll
    for (int q = 0; q < 4; ++q) {
        int usub = 4 * s + q;
        #pragma unroll
        for (int ty = 0; ty < 4; ++ty) {
            size_t bi = (size_t)(layer * 2 + d) * 1600 + ty * HID + u0 + usub;
            bias[q][ty] = bih[bi] + bhh[bi];
        }
    }
    int cur = 0;
    __syncthreads();

    for (int t = 0; t < T_LEN; ++t) {
        const int tp = d ? (T_LEN - 1 - t) : t;
        const half_t* hcur = h_pub + (size_t)(cur * 2 + d) * BATCH * KP;

        // ---- phase 1: recurrent gates via MFMA: C[32 gates][128 b] ----
        f32x4 acc[2][2] = {};
        #pragma unroll
        for (int ks = 0; ks < 13; ++ks) {
            f16x8 a0 = *(const f16x8*)(&Wsh[lr][kq + ks * 32]);
            f16x8 a1 = *(const f16x8*)(&Wsh[16 + lr][kq + ks * 32]);
            f16x8 b0 = *(const f16x8*)(hcur + (size_t)(w * 32 + lr) * KP + kq + ks * 32);
            f16x8 b1 = *(const f16x8*)(hcur + (size_t)(w * 32 + 16 + lr) * KP + kq + ks * 32);
            acc[0][0] = __builtin_amdgcn_mfma_f32_16x16x32_f16(a0, b0, acc[0][0], 0, 0, 0);
            acc[0][1] = __builtin_amdgcn_mfma_f32_16x16x32_f16(a0, b1, acc[0][1], 0, 0, 0);
            acc[1][0] = __builtin_amdgcn_mfma_f32_16x16x32_f16(a1, b0, acc[1][0], 0, 0, 0);
            acc[1][1] = __builtin_amdgcn_mfma_f32_16x16x32_f16(a1, b1, acc[1][1], 0, 0, 0);
        }
        #pragma unroll
        for (int i = 0; i < 2; ++i)
            #pragma unroll
            for (int j = 0; j < 2; ++j)
                #pragma unroll
                for (int r = 0; r < 4; ++r)
                    Gsh[i * 16 + (lane >> 4) * 4 + r][w * 32 + j * 16 + lr] = acc[i][j][r];
        __syncthreads();

        // ---- phase 2: LSTM cell, 4 adjacent units per thread ----
        const int bst = bs[tp];
        const bool active = b < bst;
        half_t* hn = h_pub + (size_t)((cur ^ 1) * 2 + d) * BATCH * KP;
        f16x4 hv4;
        float ho[4];
        #pragma unroll
        for (int q = 0; q < 4; ++q) {
            int usub = 4 * s + q;
            size_t grow = (size_t)tp * NG + (size_t)d * 1600 + u0 + usub;
            float gI = Gsh[usub][b]      + (float)gates[(grow          ) * BATCH + b] + bias[q][0];
            float gF = Gsh[8 + usub][b]  + (float)gates[(grow + 1 * HID) * BATCH + b] + bias[q][1];
            float gG = Gsh[16 + usub][b] + (float)gates[(grow + 2 * HID) * BATCH + b] + bias[q][2];
            float gO = Gsh[24 + usub][b] + (float)gates[(grow + 3 * HID) * BATCH + b] + bias[q][3];
            float iv = 1.f / (1.f + __expf(-gI));
            float fv = 1.f / (1.f + __expf(-gF));
            float gv = 1.f - 2.f / (1.f + __expf(2.f * gG));
            float ov = 1.f / (1.f + __expf(-gO));
            float cn = fv * c_reg[q] + iv * gv;
            float hnew = ov * (1.f - 2.f / (1.f + __expf(2.f * cn)));
            if (active) { c_reg[q] = cn; h_reg[q] = hnew; }
            hv4[q] = (half_t)h_reg[q];
            ho[q] = active ? h_reg[q] : 0.f;
        }
        *(f16x4*)(hn + (size_t)b * KP + u0 + 4 * s) = hv4;
        size_t obase = ((size_t)tp * BATCH + b) * 800 + (size_t)d * HID + u0 + 4 * s;
        if (out32) {
            f32x4 o4 = {ho[0], ho[1], ho[2], ho[3]};
            *(f32x4*)(out32 + obase) = o4;
        } else {
            f16x4 o4;
            o4[0] = (half_t)ho[0]; o4[1] = (half_t)ho[1];
            o4[2] = (half_t)ho[2]; o4[3] = (half_t)ho[3];
            *(f16x4*)(out16 + obase) = o4;
        }

        // ---- per-direction barrier ----
        __threadfence();
        __syncthreads();
        if (tid == 0) {
            __hip_atomic_fetch_add(&cnt[d], 1, __ATOMIC_RELEASE, __HIP_MEMORY_SCOPE_AGENT);
            const int target = BPD * (t + 1);
            while (__hip_atomic_load(&cnt[d], __ATOMIC_ACQUIRE, __HIP_MEMORY_SCOPE_AGENT) < target)
                __builtin_amdgcn_s_sleep(2);
        }
        __syncthreads();
        __threadfence();
        cur ^= 1;
    }
}

// ---------------- host ----------------
extern "C" void kernel_launch(void* const* d_in, const int* in_sizes, int n_in,
                              void* d_out, int out_size, void* d_ws, size_t ws_size,
                              hipStream_t stream) {
    const float* x    = (const float*)d_in[0];
    const float* Wih  = (const float*)d_in[1];
    const float* Whh  = (const float*)d_in[2];
    const float* bih  = (const float*)d_in[3];
    const float* bhh  = (const float*)d_in[4];
    const int*   bs   = (const int*)d_in[5];
    float*       out  = (float*)d_out;

    char* ws = (char*)d_ws;
    const size_t XBUF_B  = (size_t)T_LEN * BATCH * INDIM * 2;      // 104,857,600
    const size_t WIH_B   = (size_t)3 * 2 * 1600 * INDIM * 2;       //  15,360,000
    const size_t GATES_B = (size_t)T_LEN * NG * BATCH * 2;         // 419,430,400
    const size_t HPUB_B  = (size_t)2 * 2 * BATCH * KP * 2;         //     425,984

    half_t* xbuf0 = (half_t*)(ws);
    half_t* xbuf1 = (half_t*)(ws + XBUF_B);
    half_t* Wih16 = (half_t*)(ws + 2 * XBUF_B);
    half_t* gates = (half_t*)(ws + 2 * XBUF_B + WIH_B);
    half_t* h_pub = (half_t*)(ws + 2 * XBUF_B + WIH_B + GATES_B);
    int*    cnt   = (int*)   (ws + 2 * XBUF_B + WIH_B + GATES_B + HPUB_B);
    (void)ws_size; (void)in_sizes; (void)n_in; (void)out_size;

    cast_f32_f16<<<2048, 256, 0, stream>>>(x,   xbuf0, (size_t)T_LEN * BATCH * INDIM);
    cast_f32_f16<<<2048, 256, 0, stream>>>(Wih, Wih16, (size_t)3 * 2 * 1600 * INDIM);

    for (int l = 0; l < 3; ++l) {
        const half_t* xin    = (l == 0) ? xbuf0 : ((l == 1) ? xbuf1 : xbuf0);
        half_t*       xout16 = (l == 0) ? xbuf1 : ((l == 1) ? xbuf0 : (half_t*)nullptr);
        float*        out32  = (l == 2) ? out : (float*)nullptr;

        gemm_f16<<<dim3(512, 25), 256, 0, stream>>>(xin, Wih16 + (size_t)l * NG * INDIM, gates);

        // zero h double-buffers + barrier counters
        hipMemsetAsync(h_pub, 0, HPUB_B + 64, stream);

        const float* WhhA = Whh; const float* bihA = bih; const float* bhhA = bhh;
        const half_t* gatesA = gates; const int* bsA = bs; half_t* hpubA = h_pub;
        int* cntA = cnt; int layer = l;
        void* args[] = {(void*)&WhhA, (void*)&bihA, (void*)&bhhA, (void*)&gatesA,
                        (void*)&bsA, (void*)&hpubA, (void*)&cntA,
                        (void*)&xout16, (void*)&out32, (void*)&layer};
        hipLaunchCooperativeKernel((void*)scan_kernel, dim3(2 * BPD), dim3(256), args, 0, stream);
    }
}

// Round 3
// 13795.737 us; speedup vs baseline: 9.5361x; 3.5933x over previous
//
#include <hip/hip_runtime.h>

typedef _Float16 half_t;
typedef _Float16 f16x8 __attribute__((ext_vector_type(8)));
typedef _Float16 f16x4 __attribute__((ext_vector_type(4)));
typedef float f32x4 __attribute__((ext_vector_type(4)));
typedef unsigned int uint2v __attribute__((ext_vector_type(2)));

#define T_LEN 512
#define BATCH 128
#define INDIM 800
#define HID   400
#define NG    3200   // 2 dirs * 4H
#define KP    416    // recurrent K padded to 13*32
#define BPD   50     // blocks per direction
#define UPB   8      // units per block (32 gate rows)

// coherent-at-LLC access (bypass L1+L2) -----------------------------------
__device__ __forceinline__ f32x4 ld_coh_128(const void* p) {
    f32x4 r;
    asm volatile("global_load_dwordx4 %0, %1, off sc0 sc1" : "=v"(r) : "v"(p) : "memory");
    return r;
}
__device__ __forceinline__ void st_coh_64(void* p, uint2v v) {
    asm volatile("global_store_dwordx2 %0, %1, off sc0 sc1" :: "v"(p), "v"(v) : "memory");
}

// ---------------- cast fp32 -> fp16 ----------------
__global__ void cast_f32_f16(const float* __restrict__ src, half_t* __restrict__ dst, size_t n) {
    size_t i = (size_t)blockIdx.x * blockDim.x + threadIdx.x;
    size_t stride = (size_t)gridDim.x * blockDim.x;
    for (; i < n; i += stride) dst[i] = (half_t)src[i];
}

// ---------------- input GEMM ----------------
// A[M=T*B, 800] @ W[3200, 800]^T, output TRANSPOSED per t-tile:
// gates_T[((t*3200)+n)*128 + b]   (fp16, fp32 accum)
__global__ __launch_bounds__(256)
void gemm_f16(const half_t* __restrict__ A, const half_t* __restrict__ Bw,
              half_t* __restrict__ C) {
    __shared__ half_t As[128 * 32];
    __shared__ half_t Bs[128 * 32];
    const int tid  = threadIdx.x;
    const int m0   = blockIdx.x * 128;     // m-tile == one t (128 batches)
    const int n0   = blockIdx.y * 128;
    const int w    = tid >> 6;
    const int lane = tid & 63;
    const int wm   = (w & 1) * 64;
    const int wn   = (w >> 1) * 64;
    const int lr   = lane & 15;
    const int kb   = (lane >> 4) * 8;

    f32x4 acc[4][4] = {};

    for (int k0 = 0; k0 < INDIM; k0 += 32) {
        __syncthreads();
        #pragma unroll
        for (int it = 0; it < 2; ++it) {
            int c   = tid + it * 256;      // 512 chunks of 8 halfs
            int row = c >> 2;
            int kp  = (c & 3) * 8;
            *(f16x8*)(As + row * 32 + kp) = *(const f16x8*)(A  + (size_t)(m0 + row) * INDIM + k0 + kp);
            *(f16x8*)(Bs + row * 32 + kp) = *(const f16x8*)(Bw + (size_t)(n0 + row) * INDIM + k0 + kp);
        }
        __syncthreads();
        f16x8 a[4], b[4];
        #pragma unroll
        for (int i = 0; i < 4; ++i) a[i] = *(const f16x8*)(As + (wm + i * 16 + lr) * 32 + kb);
        #pragma unroll
        for (int j = 0; j < 4; ++j) b[j] = *(const f16x8*)(Bs + (wn + j * 16 + lr) * 32 + kb);
        // swapped operands -> C row = n (gate row), col = m (batch)
        #pragma unroll
        for (int i = 0; i < 4; ++i)
            #pragma unroll
            for (int j = 0; j < 4; ++j)
                acc[i][j] = __builtin_amdgcn_mfma_f32_16x16x32_f16(b[j], a[i], acc[i][j], 0, 0, 0);
    }

    const int t  = blockIdx.x;
    const int lq = lane >> 4;
    #pragma unroll
    for (int i = 0; i < 4; ++i)
        #pragma unroll
        for (int j = 0; j < 4; ++j)
            #pragma unroll
            for (int r = 0; r < 4; ++r) {
                int n  = n0 + wn + j * 16 + lq * 4 + r;
                int bb = wm + i * 16 + lr;
                C[((size_t)t * NG + n) * BATCH + bb] = (half_t)acc[i][j][r];
            }
}

// ---------------- persistent bidirectional scan (one layer) ----------------
// grid = 100 blocks: [0,50) fwd, [50,100) bwd; each owns 8 units (32 gate rows).
// h exchange via sc0sc1 (LLC-coherent) loads/stores; NO cache-flush fences.
__global__ __launch_bounds__(256)
void scan_kernel(const float* __restrict__ Whh_all, const float* __restrict__ bih,
                 const float* __restrict__ bhh, const half_t* __restrict__ gates,
                 const int* __restrict__ bs, half_t* __restrict__ h_pub,
                 int* __restrict__ cnt,
                 half_t* __restrict__ out16, float* __restrict__ out32, int layer) {
    __shared__ half_t Wsh[32][424];
    __shared__ float  Gsh[32][132];

    const int tid = threadIdx.x;
    const int d   = blockIdx.x / BPD;
    const int blk = blockIdx.x % BPD;
    const int u0  = blk * UPB;
    const float* Wbase = Whh_all + (size_t)(layer * 2 + d) * 1600 * HID;

    // stage 32 Whh rows (4 types x 8 units), fp32 -> fp16, zero-pad K to 416
    for (int idx = tid; idx < 32 * KP; idx += 256) {
        int g = idx / KP, k = idx - g * KP;
        int type = g >> 3, usub = g & 7;
        float v = (k < HID) ? Wbase[(size_t)(type * HID + u0 + usub) * HID + k] : 0.f;
        Wsh[g][k] = (half_t)v;
    }

    const int lane = tid & 63, w = tid >> 6;
    const int lr = lane & 15, kq = (lane >> 4) * 8;
    const int b = tid & 127, s = tid >> 7;

    float bias[4][4];
    float c_reg[4] = {0.f, 0.f, 0.f, 0.f}, h_reg[4] = {0.f, 0.f, 0.f, 0.f};
    #pragma unroll
    for (int q = 0; q < 4; ++q) {
        int usub = 4 * s + q;
        #pragma unroll
        for (int ty = 0; ty < 4; ++ty) {
            size_t bi = (size_t)(layer * 2 + d) * 1600 + ty * HID + u0 + usub;
            bias[q][ty] = bih[bi] + bhh[bi];
        }
    }
    int cur = 0;
    __syncthreads();

    for (int t = 0; t < T_LEN; ++t) {
        const int tp  = d ? (T_LEN - 1 - t) : t;
        const int bst = bs[tp];
        const half_t* hcur = h_pub + (size_t)(cur * 2 + d) * BATCH * KP;

        // ---- gate prefetch (plain cached; latency hides under h-load wait) ----
        const bool bact = b < bst;
        float gpre[4][4];
        if (bact) {
            #pragma unroll
            for (int q = 0; q < 4; ++q) {
                int usub = 4 * s + q;
                size_t grow = (size_t)tp * NG + (size_t)d * 1600 + u0 + usub;
                #pragma unroll
                for (int ty = 0; ty < 4; ++ty)
                    gpre[q][ty] = (float)gates[(grow + (size_t)ty * HID) * BATCH + b];
            }
        }

        // ---- phase 1: coherent h loads + MFMA, skipping inactive col-tiles ----
        const bool act0 = (w * 32) < bst;          // cols w*32 .. +15
        const bool act1 = (w * 32 + 16) < bst;     // cols w*32+16 .. +31
        f32x4 hb0[13], hb1[13];
        const half_t* p0 = hcur + (size_t)(w * 32 + lr) * KP + kq;
        const half_t* p1 = p0 + 16 * KP;
        if (act0) {
            #pragma unroll
            for (int ks = 0; ks < 13; ++ks) hb0[ks] = ld_coh_128(p0 + ks * 32);
        }
        if (act1) {
            #pragma unroll
            for (int ks = 0; ks < 13; ++ks) hb1[ks] = ld_coh_128(p1 + ks * 32);
        }
        asm volatile("s_waitcnt vmcnt(0)" ::: "memory");
        __builtin_amdgcn_sched_barrier(0);

        f32x4 acc[2][2] = {};
        if (act0) {
            #pragma unroll
            for (int ks = 0; ks < 13; ++ks) {
                f16x8 a0 = *(const f16x8*)(&Wsh[lr][kq + ks * 32]);
                f16x8 a1 = *(const f16x8*)(&Wsh[16 + lr][kq + ks * 32]);
                f16x8 b0 = __builtin_bit_cast(f16x8, hb0[ks]);
                acc[0][0] = __builtin_amdgcn_mfma_f32_16x16x32_f16(a0, b0, acc[0][0], 0, 0, 0);
                acc[1][0] = __builtin_amdgcn_mfma_f32_16x16x32_f16(a1, b0, acc[1][0], 0, 0, 0);
                if (act1) {
                    f16x8 b1 = __builtin_bit_cast(f16x8, hb1[ks]);
                    acc[0][1] = __builtin_amdgcn_mfma_f32_16x16x32_f16(a0, b1, acc[0][1], 0, 0, 0);
                    acc[1][1] = __builtin_amdgcn_mfma_f32_16x16x32_f16(a1, b1, acc[1][1], 0, 0, 0);
                }
            }
        }
        const int crow = (lane >> 4) * 4;
        #pragma unroll
        for (int i = 0; i < 2; ++i) {
            if (act0) {
                #pragma unroll
                for (int r = 0; r < 4; ++r)
                    Gsh[i * 16 + crow + r][w * 32 + lr] = acc[i][0][r];
            }
            if (act1) {
                #pragma unroll
                for (int r = 0; r < 4; ++r)
                    Gsh[i * 16 + crow + r][w * 32 + 16 + lr] = acc[i][1][r];
            }
        }
        __syncthreads();

        // ---- phase 2: LSTM cell, 4 adjacent units per thread ----
        half_t* hn = h_pub + (size_t)((cur ^ 1) * 2 + d) * BATCH * KP;
        size_t obase = ((size_t)tp * BATCH + b) * 800 + (size_t)d * HID + u0 + 4 * s;
        if (bact) {
            f16x4 hv4;
            #pragma unroll
            for (int q = 0; q < 4; ++q) {
                int usub = 4 * s + q;
                float gI = Gsh[usub][b]      + gpre[q][0] + bias[q][0];
                float gF = Gsh[8 + usub][b]  + gpre[q][1] + bias[q][1];
                float gG = Gsh[16 + usub][b] + gpre[q][2] + bias[q][2];
                float gO = Gsh[24 + usub][b] + gpre[q][3] + bias[q][3];
                float iv = 1.f / (1.f + __expf(-gI));
                float fv = 1.f / (1.f + __expf(-gF));
                float gv = 1.f - 2.f / (1.f + __expf(2.f * gG));
                float ov = 1.f / (1.f + __expf(-gO));
                float cn = fv * c_reg[q] + iv * gv;
                float hnew = ov * (1.f - 2.f / (1.f + __expf(2.f * cn)));
                c_reg[q] = cn; h_reg[q] = hnew;
                hv4[q] = (half_t)hnew;
            }
            st_coh_64(hn + (size_t)b * KP + u0 + 4 * s, __builtin_bit_cast(uint2v, hv4));
            if (out32) {
                f32x4 o4 = {h_reg[0], h_reg[1], h_reg[2], h_reg[3]};
                *(f32x4*)(out32 + obase) = o4;
            } else {
                f16x4 o4;
                o4[0] = (half_t)h_reg[0]; o4[1] = (half_t)h_reg[1];
                o4[2] = (half_t)h_reg[2]; o4[3] = (half_t)h_reg[3];
                *(f16x4*)(out16 + obase) = o4;
            }
        } else {
            if (out32) { f32x4 z = {0.f, 0.f, 0.f, 0.f}; *(f32x4*)(out32 + obase) = z; }
            else { f16x4 z; z[0] = z[1] = z[2] = z[3] = (half_t)0.f; *(f16x4*)(out16 + obase) = z; }
        }

        // ---- per-direction barrier: drain stores, relaxed signal, coherent spin ----
        if (t != T_LEN - 1) {
            asm volatile("s_waitcnt vmcnt(0)" ::: "memory");
            __syncthreads();
            if (tid == 0) {
                __hip_atomic_fetch_add(&cnt[d], 1, __ATOMIC_RELAXED, __HIP_MEMORY_SCOPE_AGENT);
                const int target = BPD * (t + 1);
                int v;
                do {
                    __builtin_amdgcn_s_sleep(1);
                    asm volatile("global_load_dword %0, %1, off sc0 sc1\ns_waitcnt vmcnt(0)"
                                 : "=v"(v) : "v"((const void*)&cnt[d]) : "memory");
                } while (v < target);
            }
            __syncthreads();
        }
        cur ^= 1;
    }
}

// ---------------- host ----------------
extern "C" void kernel_launch(void* const* d_in, const int* in_sizes, int n_in,
                              void* d_out, int out_size, void* d_ws, size_t ws_size,
                              hipStream_t stream) {
    const float* x    = (const float*)d_in[0];
    const float* Wih  = (const float*)d_in[1];
    const float* Whh  = (const float*)d_in[2];
    const float* bih  = (const float*)d_in[3];
    const float* bhh  = (const float*)d_in[4];
    const int*   bs   = (const int*)d_in[5];
    float*       out  = (float*)d_out;

    char* ws = (char*)d_ws;
    const size_t XBUF_B  = (size_t)T_LEN * BATCH * INDIM * 2;      // 104,857,600
    const size_t WIH_B   = (size_t)3 * 2 * 1600 * INDIM * 2;       //  15,360,000
    const size_t GATES_B = (size_t)T_LEN * NG * BATCH * 2;         // 419,430,400
    const size_t HPUB_B  = (size_t)2 * 2 * BATCH * KP * 2;         //     425,984

    half_t* xbuf0 = (half_t*)(ws);
    half_t* xbuf1 = (half_t*)(ws + XBUF_B);
    half_t* Wih16 = (half_t*)(ws + 2 * XBUF_B);
    half_t* gates = (half_t*)(ws + 2 * XBUF_B + WIH_B);
    half_t* h_pub = (half_t*)(ws + 2 * XBUF_B + WIH_B + GATES_B);
    int*    cnt   = (int*)   (ws + 2 * XBUF_B + WIH_B + GATES_B + HPUB_B);
    (void)ws_size; (void)in_sizes; (void)n_in; (void)out_size;

    cast_f32_f16<<<2048, 256, 0, stream>>>(x,   xbuf0, (size_t)T_LEN * BATCH * INDIM);
    cast_f32_f16<<<2048, 256, 0, stream>>>(Wih, Wih16, (size_t)3 * 2 * 1600 * INDIM);

    for (int l = 0; l < 3; ++l) {
        const half_t* xin    = (l == 0) ? xbuf0 : ((l == 1) ? xbuf1 : xbuf0);
        half_t*       xout16 = (l == 0) ? xbuf1 : ((l == 1) ? xbuf0 : (half_t*)nullptr);
        float*        out32  = (l == 2) ? out : (float*)nullptr;

        gemm_f16<<<dim3(512, 25), 256, 0, stream>>>(xin, Wih16 + (size_t)l * NG * INDIM, gates);

        // zero h double-buffers + barrier counters (packet fence makes this
        // visible to the scan's LLC-coherent accesses)
        hipMemsetAsync(h_pub, 0, HPUB_B + 64, stream);

        const float* WhhA = Whh; const float* bihA = bih; const float* bhhA = bhh;
        const half_t* gatesA = gates; const int* bsA = bs; half_t* hpubA = h_pub;
        int* cntA = cnt; int layer = l;
        void* args[] = {(void*)&WhhA, (void*)&bihA, (void*)&bhhA, (void*)&gatesA,
                        (void*)&bsA, (void*)&hpubA, (void*)&cntA,
                        (void*)&xout16, (void*)&out32, (void*)&layer};
        hipLaunchCooperativeKernel((void*)scan_kernel, dim3(2 * BPD), dim3(256), args, 0, stream);
    }
}

// Round 4
// 10340.158 us; speedup vs baseline: 12.7230x; 1.3342x over previous
//
#include <hip/hip_runtime.h>

typedef _Float16 half_t;
typedef _Float16 f16x8 __attribute__((ext_vector_type(8)));
typedef _Float16 f16x4 __attribute__((ext_vector_type(4)));
typedef float f32x4 __attribute__((ext_vector_type(4)));
typedef unsigned int uint2v __attribute__((ext_vector_type(2)));

#define T_LEN 512
#define BATCH 128
#define INDIM 800
#define HID   400
#define NG    3200   // 2 dirs * 4H
#define KP    416    // recurrent K padded to 13*32
#define BPD   50     // blocks per direction
#define UPB   8      // units per block (32 gate rows)

// coherent-at-LLC access (bypass L1+L2) -----------------------------------
__device__ __forceinline__ f32x4 ld_coh_128(const void* p) {
    f32x4 r;
    asm volatile("global_load_dwordx4 %0, %1, off sc0 sc1" : "=v"(r) : "v"(p) : "memory");
    return r;
}
__device__ __forceinline__ void st_coh_64(void* p, uint2v v) {
    asm volatile("global_store_dwordx2 %0, %1, off sc0 sc1" :: "v"(p), "v"(v) : "memory");
}
__device__ __forceinline__ void st_coh_32(void* p, int v) {
    asm volatile("global_store_dword %0, %1, off sc0 sc1" :: "v"(p), "v"(v) : "memory");
}
__device__ __forceinline__ int ld_coh_32(const void* p) {
    int v;
    asm volatile("global_load_dword %0, %1, off sc0 sc1\ns_waitcnt vmcnt(0)"
                 : "=v"(v) : "v"(p) : "memory");
    return v;
}

// ---------------- cast fp32 -> fp16 ----------------
__global__ void cast_f32_f16(const float* __restrict__ src, half_t* __restrict__ dst, size_t n) {
    size_t i = (size_t)blockIdx.x * blockDim.x + threadIdx.x;
    size_t stride = (size_t)gridDim.x * blockDim.x;
    for (; i < n; i += stride) dst[i] = (half_t)src[i];
}

// ---------------- input GEMM ----------------
// A[M=T*B, 800] @ W[3200, 800]^T, output TRANSPOSED per t-tile:
// gates_T[((t*3200)+n)*128 + b]   (fp16, fp32 accum)
__global__ __launch_bounds__(256)
void gemm_f16(const half_t* __restrict__ A, const half_t* __restrict__ Bw,
              half_t* __restrict__ C) {
    __shared__ half_t As[128 * 32];
    __shared__ half_t Bs[128 * 32];
    const int tid  = threadIdx.x;
    const int m0   = blockIdx.x * 128;     // m-tile == one t (128 batches)
    const int n0   = blockIdx.y * 128;
    const int w    = tid >> 6;
    const int lane = tid & 63;
    const int wm   = (w & 1) * 64;
    const int wn   = (w >> 1) * 64;
    const int lr   = lane & 15;
    const int kb   = (lane >> 4) * 8;

    f32x4 acc[4][4] = {};

    for (int k0 = 0; k0 < INDIM; k0 += 32) {
        __syncthreads();
        #pragma unroll
        for (int it = 0; it < 2; ++it) {
            int c   = tid + it * 256;      // 512 chunks of 8 halfs
            int row = c >> 2;
            int kp  = (c & 3) * 8;
            *(f16x8*)(As + row * 32 + kp) = *(const f16x8*)(A  + (size_t)(m0 + row) * INDIM + k0 + kp);
            *(f16x8*)(Bs + row * 32 + kp) = *(const f16x8*)(Bw + (size_t)(n0 + row) * INDIM + k0 + kp);
        }
        __syncthreads();
        f16x8 a[4], b[4];
        #pragma unroll
        for (int i = 0; i < 4; ++i) a[i] = *(const f16x8*)(As + (wm + i * 16 + lr) * 32 + kb);
        #pragma unroll
        for (int j = 0; j < 4; ++j) b[j] = *(const f16x8*)(Bs + (wn + j * 16 + lr) * 32 + kb);
        // swapped operands -> C row = n (gate row), col = m (batch)
        #pragma unroll
        for (int i = 0; i < 4; ++i)
            #pragma unroll
            for (int j = 0; j < 4; ++j)
                acc[i][j] = __builtin_amdgcn_mfma_f32_16x16x32_f16(b[j], a[i], acc[i][j], 0, 0, 0);
    }

    const int t  = blockIdx.x;
    const int lq = lane >> 4;
    #pragma unroll
    for (int i = 0; i < 4; ++i)
        #pragma unroll
        for (int j = 0; j < 4; ++j)
            #pragma unroll
            for (int r = 0; r < 4; ++r) {
                int n  = n0 + wn + j * 16 + lq * 4 + r;
                int bb = wm + i * 16 + lr;
                C[((size_t)t * NG + n) * BATCH + bb] = (half_t)acc[i][j][r];
            }
}

// ---------------- persistent bidirectional scan (one layer) ----------------
// grid = 100 blocks: [0,50) fwd, [50,100) bwd; each owns 8 units (32 gate rows).
// h exchange via sc0sc1 (LLC-coherent) loads/stores; flag-array barrier.
__global__ __launch_bounds__(256)
void scan_kernel(const float* __restrict__ Whh_all, const float* __restrict__ bih,
                 const float* __restrict__ bhh, const half_t* __restrict__ gates,
                 const int* __restrict__ bs, half_t* __restrict__ h_pub,
                 int* __restrict__ flags,
                 half_t* __restrict__ out16, float* __restrict__ out32, int layer) {
    __shared__ half_t Wsh[32][424];
    __shared__ float  Gsh[32][132];

    const int tid = threadIdx.x;
    const int d   = blockIdx.x / BPD;
    const int blk = blockIdx.x % BPD;
    const int u0  = blk * UPB;
    const float* Wbase = Whh_all + (size_t)(layer * 2 + d) * 1600 * HID;

    // stage 32 Whh rows (4 types x 8 units), fp32 -> fp16, zero-pad K to 416
    for (int idx = tid; idx < 32 * KP; idx += 256) {
        int g = idx / KP, k = idx - g * KP;
        int type = g >> 3, usub = g & 7;
        float v = (k < HID) ? Wbase[(size_t)(type * HID + u0 + usub) * HID + k] : 0.f;
        Wsh[g][k] = (half_t)v;
    }

    const int lane = tid & 63, w = tid >> 6;
    const int lr = lane & 15, kq = (lane >> 4) * 8;
    const int b = tid & 127, s = tid >> 7;

    float bias[4][4];
    float c_reg[4] = {0.f, 0.f, 0.f, 0.f}, h_reg[4] = {0.f, 0.f, 0.f, 0.f};
    #pragma unroll
    for (int q = 0; q < 4; ++q) {
        int usub = 4 * s + q;
        #pragma unroll
        for (int ty = 0; ty < 4; ++ty) {
            size_t bi = (size_t)(layer * 2 + d) * 1600 + ty * HID + u0 + usub;
            bias[q][ty] = bih[bi] + bhh[bi];
        }
    }

    // pipelined gate/output pointers (advance by +/- one timestep per iter)
    const long gstep = (long)(d ? -1 : 1) * (long)NG * BATCH;
    const long ostep = (long)(d ? -1 : 1) * (long)BATCH * 800;
    const int  t0p   = d ? (T_LEN - 1) : 0;
    const half_t* gptr = gates + (size_t)t0p * NG * BATCH + (size_t)d * 1600 * BATCH
                       + (size_t)(u0 + 4 * s) * BATCH + b;
    float*  op32 = out32 ? out32 + (size_t)t0p * BATCH * 800 + (size_t)b * 800 + d * HID + u0 + 4 * s
                         : (float*)nullptr;
    half_t* op16 = out16 ? out16 + (size_t)t0p * BATCH * 800 + (size_t)b * 800 + d * HID + u0 + 4 * s
                         : (half_t*)nullptr;

#define GPRE_LOAD() do {                                                    \
        _Pragma("unroll") for (int q = 0; q < 4; ++q)                       \
            _Pragma("unroll") for (int ty = 0; ty < 4; ++ty)                \
                gpre[q][ty] = (float)gptr[q * BATCH + ty * HID * BATCH];    \
    } while (0)

    float gpre[4][4];
    int bst = bs[t0p];
    bool bact = b < bst;
    if (bact) GPRE_LOAD();

    int cur = 0;
    __syncthreads();

    for (int t = 0; t < T_LEN; ++t) {
        const bool last = (t == T_LEN - 1);
        const half_t* hcur = h_pub + (size_t)(cur * 2 + d) * BATCH * KP;

        // ---- phase 1: coherent h loads + MFMA, skipping inactive col-tiles ----
        const bool act0 = (w * 32) < bst;          // cols w*32 .. +15
        const bool act1 = (w * 32 + 16) < bst;     // cols w*32+16 .. +31
        f32x4 hb0[13], hb1[13];
        const half_t* p0 = hcur + (size_t)(w * 32 + lr) * KP + kq;
        const half_t* p1 = p0 + 16 * KP;
        if (act0) {
            #pragma unroll
            for (int ks = 0; ks < 13; ++ks) hb0[ks] = ld_coh_128(p0 + ks * 32);
        }
        if (act1) {
            #pragma unroll
            for (int ks = 0; ks < 13; ++ks) hb1[ks] = ld_coh_128(p1 + ks * 32);
        }
        asm volatile("s_waitcnt vmcnt(0)" ::: "memory");
        __builtin_amdgcn_sched_barrier(0);

        f32x4 acc[2][2] = {};
        if (act0) {
            #pragma unroll
            for (int ks = 0; ks < 13; ++ks) {
                f16x8 a0 = *(const f16x8*)(&Wsh[lr][kq + ks * 32]);
                f16x8 a1 = *(const f16x8*)(&Wsh[16 + lr][kq + ks * 32]);
                f16x8 b0 = __builtin_bit_cast(f16x8, hb0[ks]);
                acc[0][0] = __builtin_amdgcn_mfma_f32_16x16x32_f16(a0, b0, acc[0][0], 0, 0, 0);
                acc[1][0] = __builtin_amdgcn_mfma_f32_16x16x32_f16(a1, b0, acc[1][0], 0, 0, 0);
                if (act1) {
                    f16x8 b1 = __builtin_bit_cast(f16x8, hb1[ks]);
                    acc[0][1] = __builtin_amdgcn_mfma_f32_16x16x32_f16(a0, b1, acc[0][1], 0, 0, 0);
                    acc[1][1] = __builtin_amdgcn_mfma_f32_16x16x32_f16(a1, b1, acc[1][1], 0, 0, 0);
                }
            }
        }
        const int crow = (lane >> 4) * 4;
        #pragma unroll
        for (int i = 0; i < 2; ++i) {
            if (act0) {
                #pragma unroll
                for (int r = 0; r < 4; ++r)
                    Gsh[i * 16 + crow + r][w * 32 + lr] = acc[i][0][r];
            }
            if (act1) {
                #pragma unroll
                for (int r = 0; r < 4; ++r)
                    Gsh[i * 16 + crow + r][w * 32 + 16 + lr] = acc[i][1][r];
            }
        }
        __syncthreads();

        // ---- phase 2: LSTM cell, 4 adjacent units per thread ----
        if (bact) {
            #pragma unroll
            for (int q = 0; q < 4; ++q) {
                int usub = 4 * s + q;
                float gI = Gsh[usub][b]      + gpre[q][0] + bias[q][0];
                float gF = Gsh[8 + usub][b]  + gpre[q][1] + bias[q][1];
                float gG = Gsh[16 + usub][b] + gpre[q][2] + bias[q][2];
                float gO = Gsh[24 + usub][b] + gpre[q][3] + bias[q][3];
                float iv = 1.f / (1.f + __expf(-gI));
                float fv = 1.f / (1.f + __expf(-gF));
                float gv = 1.f - 2.f / (1.f + __expf(2.f * gG));
                float ov = 1.f / (1.f + __expf(-gO));
                float cn = fv * c_reg[q] + iv * gv;
                float hnew = ov * (1.f - 2.f / (1.f + __expf(2.f * cn)));
                c_reg[q] = cn; h_reg[q] = hnew;
            }
        }

        // ---- publish h + flag signal (skipped at last step) ----
        if (!last) {
            if (bact) {
                half_t* hn = h_pub + (size_t)((cur ^ 1) * 2 + d) * BATCH * KP;
                f16x4 hv4;
                hv4[0] = (half_t)h_reg[0]; hv4[1] = (half_t)h_reg[1];
                hv4[2] = (half_t)h_reg[2]; hv4[3] = (half_t)h_reg[3];
                st_coh_64(hn + (size_t)b * KP + u0 + 4 * s, __builtin_bit_cast(uint2v, hv4));
            }
            asm volatile("s_waitcnt vmcnt(0)" ::: "memory");
            __syncthreads();
            if (tid == 0) st_coh_32(&flags[d * 64 + blk], t + 1);
        }

        // ---- output stores (off critical path) ----
        if (bact) {
            if (op32) { f32x4 o4 = {h_reg[0], h_reg[1], h_reg[2], h_reg[3]}; *(f32x4*)op32 = o4; }
            else {
                f16x4 o4;
                o4[0] = (half_t)h_reg[0]; o4[1] = (half_t)h_reg[1];
                o4[2] = (half_t)h_reg[2]; o4[3] = (half_t)h_reg[3];
                *(f16x4*)op16 = o4;
            }
        } else {
            if (op32) { f32x4 z = {0.f, 0.f, 0.f, 0.f}; *(f32x4*)op32 = z; }
            else { f16x4 z; z[0] = z[1] = z[2] = z[3] = (half_t)0.f; *(f16x4*)op16 = z; }
        }
        if (op32) op32 += ostep; else op16 += ostep;

        // ---- prefetch next gates during barrier wait, then spin ----
        if (!last) {
            gptr += gstep;
            const int bst_next = bs[d ? (T_LEN - 2 - t) : (t + 1)];
            const bool bact_next = b < bst_next;
            if (bact_next) GPRE_LOAD();
            bst = bst_next; bact = bact_next;

            if (tid < 64) {
                const int* fp = flags + d * 64 + tid;
                int pred;
                do {
                    int v = (tid < BPD) ? ld_coh_32(fp) : 0x7fffffff;
                    pred = (v >= t + 1);
                } while (!__all(pred));
            }
            __syncthreads();
        }
        cur ^= 1;
    }
#undef GPRE_LOAD
}

// ---------------- host ----------------
extern "C" void kernel_launch(void* const* d_in, const int* in_sizes, int n_in,
                              void* d_out, int out_size, void* d_ws, size_t ws_size,
                              hipStream_t stream) {
    const float* x    = (const float*)d_in[0];
    const float* Wih  = (const float*)d_in[1];
    const float* Whh  = (const float*)d_in[2];
    const float* bih  = (const float*)d_in[3];
    const float* bhh  = (const float*)d_in[4];
    const int*   bs   = (const int*)d_in[5];
    float*       out  = (float*)d_out;

    char* ws = (char*)d_ws;
    const size_t XBUF_B  = (size_t)T_LEN * BATCH * INDIM * 2;      // 104,857,600
    const size_t WIH_B   = (size_t)3 * 2 * 1600 * INDIM * 2;       //  15,360,000
    const size_t GATES_B = (size_t)T_LEN * NG * BATCH * 2;         // 419,430,400
    const size_t HPUB_B  = (size_t)2 * 2 * BATCH * KP * 2;         //     425,984

    half_t* xbuf0 = (half_t*)(ws);
    half_t* xbuf1 = (half_t*)(ws + XBUF_B);
    half_t* Wih16 = (half_t*)(ws + 2 * XBUF_B);
    half_t* gates = (half_t*)(ws + 2 * XBUF_B + WIH_B);
    half_t* h_pub = (half_t*)(ws + 2 * XBUF_B + WIH_B + GATES_B);
    int*    flags = (int*)   (ws + 2 * XBUF_B + WIH_B + GATES_B + HPUB_B);
    (void)ws_size; (void)in_sizes; (void)n_in; (void)out_size;

    cast_f32_f16<<<2048, 256, 0, stream>>>(x,   xbuf0, (size_t)T_LEN * BATCH * INDIM);
    cast_f32_f16<<<2048, 256, 0, stream>>>(Wih, Wih16, (size_t)3 * 2 * 1600 * INDIM);

    for (int l = 0; l < 3; ++l) {
        const half_t* xin    = (l == 0) ? xbuf0 : ((l == 1) ? xbuf1 : xbuf0);
        half_t*       xout16 = (l == 0) ? xbuf1 : ((l == 1) ? xbuf0 : (half_t*)nullptr);
        float*        out32  = (l == 2) ? out : (float*)nullptr;

        gemm_f16<<<dim3(512, 25), 256, 0, stream>>>(xin, Wih16 + (size_t)l * NG * INDIM, gates);

        // zero h double-buffers + barrier flags (end-of-blit release makes
        // this visible to the scan's LLC-coherent accesses)
        hipMemsetAsync(h_pub, 0, HPUB_B + 512, stream);

        const float* WhhA = Whh; const float* bihA = bih; const float* bhhA = bhh;
        const half_t* gatesA = gates; const int* bsA = bs; half_t* hpubA = h_pub;
        int* flagsA = flags; int layer = l;
        void* args[] = {(void*)&WhhA, (void*)&bihA, (void*)&bhhA, (void*)&gatesA,
                        (void*)&bsA, (void*)&hpubA, (void*)&flagsA,
                        (void*)&xout16, (void*)&out32, (void*)&layer};
        hipLaunchCooperativeKernel((void*)scan_kernel, dim3(2 * BPD), dim3(256), args, 0, stream);
    }
}